// Round 2
// baseline (113.579 us; speedup 1.0000x reference)
//
#include <hip/hip_runtime.h>

// Problem: B=128, V=1024, T=1024, C=1024
#define B_ 128
#define V_ 1024
#define T_ 1024
#define C_ 1024
#define KK 2048  // T_ + V_

// Degree-9 Taylor coefficients of f(s) = exp(tanh(s)).
constexpr float C9v[10] = {1.0f,          1.0f,          0.5f,
                           -0.166666667f, -0.291666667f, -0.025f,
                           0.134722222f,  0.054563493f,  -0.051165675f,
                           -0.041377307f};
// Binomial coefficients C(j,p), j<=9
constexpr float BN[10][10] = {
    {1, 0, 0, 0, 0, 0, 0, 0, 0, 0},
    {1, 1, 0, 0, 0, 0, 0, 0, 0, 0},
    {1, 2, 1, 0, 0, 0, 0, 0, 0, 0},
    {1, 3, 3, 1, 0, 0, 0, 0, 0, 0},
    {1, 4, 6, 4, 1, 0, 0, 0, 0, 0},
    {1, 5, 10, 10, 5, 1, 0, 0, 0, 0},
    {1, 6, 15, 20, 15, 6, 1, 0, 0, 0},
    {1, 7, 21, 35, 35, 21, 7, 1, 0, 0},
    {1, 8, 28, 56, 70, 56, 28, 8, 1, 0},
    {1, 9, 36, 84, 126, 126, 84, 36, 9, 1}};

// Fused moment kernel (round-0 known-good shape: 128 blocks x 256 threads,
// 1 block/CU; moment tables in VGPRs).
//  P0: M_{p,q} = sum_t w_t^p x_t^q            (p+q <= 10, 66 moments)
//  P1: per v: d_i = gamma-shifted coeffs; T1 = denom, T2 = sum e*x;
//      St[b][1024+v] = T2/T1 (text_score); vod = alpha/T1
//  P2: N_{p,q} = sum_v C(p+q,p) d_{p+q} a^p b^q vod   (p+q <= 9, 55 moments)
//  P3: per t: St[b][t] = sum_{p,q} w^p x^q N_{p,q}    (visual_score)
// NOTE (R1 post-mortem): do NOT try to host M/N in SGPRs via readfirstlane —
// 121 values exceed the ~102-SGPR/wave allocation cap, and wider blocks only
// multiply total butterfly-reduce instructions. This 256-thread VGPR version
// measured fastest.
__global__ __launch_bounds__(256, 1) void kf_moments(
    const float* __restrict__ visual, const float* __restrict__ text,
    const float* __restrict__ w_vis, const float* __restrict__ w_text,
    const float* __restrict__ bias, float* __restrict__ St) {
  const int b = blockIdx.x;
  const int tid = threadIdx.x;
  const int lane = tid & 63, wave = tid >> 6;
  __shared__ float Rw[4][66];
  __shared__ float fin[66];

  // ---------- P0: t-moments ----------
  float mac[66];
#pragma unroll
  for (int r = 0; r < 66; ++r) mac[r] = 0.f;
#pragma unroll
  for (int j = 0; j < 4; ++j) {
    const int t = tid + 256 * j;
    const float w = w_vis[t];
    const float x = text[b * T_ + t];
    float wp[11], xq[11];
    wp[0] = 1.f;
    xq[0] = 1.f;
#pragma unroll
    for (int k = 1; k <= 10; ++k) {
      wp[k] = wp[k - 1] * w;
      xq[k] = xq[k - 1] * x;
    }
#pragma unroll
    for (int i = 0; i <= 10; ++i)
#pragma unroll
      for (int p = 0; p <= i; ++p)
        mac[i * (i + 1) / 2 + p] =
            fmaf(wp[p], xq[i - p], mac[i * (i + 1) / 2 + p]);
  }
#pragma unroll
  for (int m = 1; m <= 32; m <<= 1)
#pragma unroll
    for (int r = 0; r < 66; ++r) mac[r] += __shfl_xor(mac[r], m, 64);
  if (lane == 0) {
#pragma unroll
    for (int r = 0; r < 66; ++r) Rw[wave][r] = mac[r];
  }
  __syncthreads();
  if (tid < 66) fin[tid] = (Rw[0][tid] + Rw[1][tid]) + (Rw[2][tid] + Rw[3][tid]);
  __syncthreads();
  float M[66];
#pragma unroll
  for (int r = 0; r < 66; ++r) M[r] = fin[r];

  // ---------- P1 + P2: per-v eval and v-moments ----------
  float nac[55];
#pragma unroll
  for (int r = 0; r < 55; ++r) nac[r] = 0.f;
#pragma unroll
  for (int j = 0; j < 4; ++j) {
    const int v = tid + 256 * j;
    const float al = visual[b * V_ + v];
    const float be = w_text[v];
    const float ga = bias[v];
    float ap[10], bq[10];
    ap[0] = 1.f;
    bq[0] = 1.f;
#pragma unroll
    for (int k = 1; k <= 9; ++k) {
      ap[k] = ap[k - 1] * al;
      bq[k] = bq[k - 1] * be;
    }
    // gamma-shift: d_i = sum_{k} c_{i+k} C(i+k,i) ga^k   (Horner)
    float d[10];
#pragma unroll
    for (int i = 0; i < 10; ++i) {
      float a = 0.f;
#pragma unroll
      for (int jj = 9; jj >= i; --jj) a = fmaf(a, ga, C9v[jj] * BN[jj][i]);
      d[i] = a;
    }
    float T1 = 0.f, T2 = 0.f;
    float h[55];
#pragma unroll
    for (int i = 0; i <= 9; ++i)
#pragma unroll
      for (int p = 0; p <= i; ++p) {
        const int ix = i * (i + 1) / 2 + p;
        const int ix2 = (i + 1) * (i + 2) / 2 + p;  // (p, q+1)
        h[ix] = d[i] * BN[i][p] * ap[p] * bq[i - p];
        T1 = fmaf(h[ix], M[ix], T1);
        T2 = fmaf(h[ix], M[ix2], T2);
      }
    const float rd = 1.0f / T1;
    St[b * KK + T_ + v] = T2 * rd;  // text_score
    const float vod = al * rd;
#pragma unroll
    for (int r = 0; r < 55; ++r) nac[r] = fmaf(h[r], vod, nac[r]);
  }
#pragma unroll
  for (int m = 1; m <= 32; m <<= 1)
#pragma unroll
    for (int r = 0; r < 55; ++r) nac[r] += __shfl_xor(nac[r], m, 64);
  if (lane == 0) {
#pragma unroll
    for (int r = 0; r < 55; ++r) Rw[wave][r] = nac[r];
  }
  __syncthreads();
  if (tid < 55) fin[tid] = (Rw[0][tid] + Rw[1][tid]) + (Rw[2][tid] + Rw[3][tid]);
  __syncthreads();
  float N[55];
#pragma unroll
  for (int r = 0; r < 55; ++r) N[r] = fin[r];

  // ---------- P3: per-t eval ----------
#pragma unroll
  for (int j = 0; j < 4; ++j) {
    const int t = tid + 256 * j;
    const float w = w_vis[t];
    const float x = text[b * T_ + t];
    float wp[10], xq[10];
    wp[0] = 1.f;
    xq[0] = 1.f;
#pragma unroll
    for (int k = 1; k <= 9; ++k) {
      wp[k] = wp[k - 1] * w;
      xq[k] = xq[k - 1] * x;
    }
    float vs = 0.f;
#pragma unroll
    for (int i = 0; i <= 9; ++i)
#pragma unroll
      for (int p = 0; p <= i; ++p)
        vs = fmaf(wp[p] * xq[i - p], N[i * (i + 1) / 2 + p], vs);
    St[b * KK + t] = vs;  // visual_score
  }
}

// K3: split-K fp32 GEMM, re-tiled for LDS throughput (the R2 change).
// part[z][b][c] = sum_{k in slab z} St[b][k] * Wcat[c][k].
// Tile: full 128b x 128c, K-slab = 64 (32 slabs). Grid (32,8) = 256 blocks
// = 1 block/CU. Micro-tile 8x8 (rows {4mb+i,4mb+64+i} x cols {4mc+u,
// 4mc+64+u}) -> 64 B LDS per 64 FMA = 1.0 B/FMA (was 3.0).
// Bank analysis (stride 132 floats): staging writes (lanes kq&3 over k,
// rr over row) hit (16(kq&1)+4u+rr)%32 -> all 32 banks, 2-way = free;
// compute reads at col 4m and 4m+64 are 16 distinct 16B slots -> 2-way = free.
#define KC3 64
__global__ __launch_bounds__(256, 1) void k3_gemm(
    const float* __restrict__ St, const float* __restrict__ W_fv,
    const float* __restrict__ W_ft, float* __restrict__ part) {
  __shared__ float Ss[KC3][132];  // [k][b], b = 0..127
  __shared__ float Ws[KC3][132];  // [k][c], c = 0..127
  const int zz = blockIdx.x;       // k-slab 0..31 (x-major: same-z%8 -> same XCD)
  const int cb = blockIdx.y * 128; // c-tile
  const int ks = zz * KC3;
  const float* __restrict__ W = (ks < T_) ? (W_fv + ks) : (W_ft + (ks - T_));
  const int tid = threadIdx.x;
  const int kq = tid & 3, rr = tid >> 2;  // staging: k-quad 0..3, row 0..63

  // ---- stage St slab: 64k x 128b (transposed; k-contiguous global loads) ----
#pragma unroll
  for (int jb = 0; jb < 2; ++jb) {
    const int brow = rr + 64 * jb;
#pragma unroll
    for (int jk = 0; jk < 4; ++jk) {
      const int k0 = 4 * kq + 16 * jk;
      float4 g = *(const float4*)&St[brow * KK + ks + k0];
      Ss[k0 + 0][brow] = g.x;
      Ss[k0 + 1][brow] = g.y;
      Ss[k0 + 2][brow] = g.z;
      Ss[k0 + 3][brow] = g.w;
    }
  }
  // ---- stage W slab: 64k x 128c ----
#pragma unroll
  for (int jc = 0; jc < 2; ++jc) {
    const int c = rr + 64 * jc;
#pragma unroll
    for (int jk = 0; jk < 4; ++jk) {
      const int k0 = 4 * kq + 16 * jk;
      float4 g = *(const float4*)&W[(cb + c) * 1024 + k0];
      Ws[k0 + 0][c] = g.x;
      Ws[k0 + 1][c] = g.y;
      Ws[k0 + 2][c] = g.z;
      Ws[k0 + 3][c] = g.w;
    }
  }
  __syncthreads();

  const int mc = tid & 15, mb = tid >> 4;
  float acc[8][8] = {};
#pragma unroll 4
  for (int k = 0; k < KC3; ++k) {
    const float4 s0 = *(const float4*)&Ss[k][4 * mb];
    const float4 s1 = *(const float4*)&Ss[k][4 * mb + 64];
    const float4 w0 = *(const float4*)&Ws[k][4 * mc];
    const float4 w1 = *(const float4*)&Ws[k][4 * mc + 64];
    const float sv[8] = {s0.x, s0.y, s0.z, s0.w, s1.x, s1.y, s1.z, s1.w};
    const float wv[8] = {w0.x, w0.y, w0.z, w0.w, w1.x, w1.y, w1.z, w1.w};
#pragma unroll
    for (int i = 0; i < 8; ++i)
#pragma unroll
      for (int u = 0; u < 8; ++u) acc[i][u] = fmaf(sv[i], wv[u], acc[i][u]);
  }

  float* __restrict__ P = part + (size_t)zz * (B_ * C_);
#pragma unroll
  for (int ih = 0; ih < 2; ++ih)
#pragma unroll
    for (int i = 0; i < 4; ++i) {
      const int row = 4 * mb + 64 * ih + i;
#pragma unroll
      for (int jh = 0; jh < 2; ++jh) {
        float4 o = make_float4(acc[ih * 4 + i][jh * 4 + 0],
                               acc[ih * 4 + i][jh * 4 + 1],
                               acc[ih * 4 + i][jh * 4 + 2],
                               acc[ih * 4 + i][jh * 4 + 3]);
        *(float4*)&P[row * C_ + cb + 4 * mc + 64 * jh] = o;
      }
    }
}

// K4: out[i] = relu(sum_{z<32} part[z][i] + b_fv[c] + b_ft[c]), float4-wide.
__global__ __launch_bounds__(256) void k4_reduce_biasrelu(
    const float* __restrict__ part, const float* __restrict__ b_fv,
    const float* __restrict__ b_ft, float* __restrict__ out) {
  const int i4 = (blockIdx.x * 256 + threadIdx.x) * 4;
  float4 s = *(const float4*)&part[i4];
#pragma unroll 4
  for (int z = 1; z < 32; ++z) {
    float4 p = *(const float4*)&part[(size_t)z * (B_ * C_) + i4];
    s.x += p.x;
    s.y += p.y;
    s.z += p.z;
    s.w += p.w;
  }
  const int c = i4 & (C_ - 1);
  float4 bf = *(const float4*)&b_fv[c];
  float4 bt = *(const float4*)&b_ft[c];
  float4 o;
  o.x = fmaxf(s.x + bf.x + bt.x, 0.f);
  o.y = fmaxf(s.y + bf.y + bt.y, 0.f);
  o.z = fmaxf(s.z + bf.z + bt.z, 0.f);
  o.w = fmaxf(s.w + bf.w + bt.w, 0.f);
  *(float4*)&out[i4] = o;
}

extern "C" void kernel_launch(void* const* d_in, const int* in_sizes, int n_in,
                              void* d_out, int out_size, void* d_ws, size_t ws_size,
                              hipStream_t stream) {
  const float* visual = (const float*)d_in[0];  // [B,V]
  const float* text   = (const float*)d_in[1];  // [B,T]
  const float* w_vis  = (const float*)d_in[2];  // [T]
  const float* w_text = (const float*)d_in[3];  // [V]
  const float* bias   = (const float*)d_in[4];  // [V]
  const float* W_fv   = (const float*)d_in[5];  // [C,T]
  const float* b_fv   = (const float*)d_in[6];  // [C]
  const float* W_ft   = (const float*)d_in[7];  // [C,V]
  const float* b_ft   = (const float*)d_in[8];  // [C]
  float* out = (float*)d_out;                   // [B,C]

  // ws layout (floats): St[B][2048] | part[32][B*C]   (~17 MB)
  float* St = (float*)d_ws;
  float* part = St + (size_t)B_ * KK;

  kf_moments<<<dim3(B_), dim3(256), 0, stream>>>(visual, text, w_vis, w_text,
                                                 bias, St);
  k3_gemm<<<dim3(32, 8), dim3(256), 0, stream>>>(St, W_fv, W_ft, part);
  k4_reduce_biasrelu<<<dim3(B_ * C_ / 1024), dim3(256), 0, stream>>>(
      part, b_fv, b_ft, out);
}

// Round 3
// 112.859 us; speedup vs baseline: 1.0064x; 1.0064x over previous
//
#include <hip/hip_runtime.h>

// Problem: B=128, V=1024, T=1024, C=1024
#define B_ 128
#define V_ 1024
#define T_ 1024
#define C_ 1024
#define KK 2048  // T_ + V_

// Degree-9 Taylor coefficients of f(s) = exp(tanh(s)).
constexpr float C9v[10] = {1.0f,          1.0f,          0.5f,
                           -0.166666667f, -0.291666667f, -0.025f,
                           0.134722222f,  0.054563493f,  -0.051165675f,
                           -0.041377307f};
// Binomial coefficients C(j,p), j<=9
constexpr float BN[10][10] = {
    {1, 0, 0, 0, 0, 0, 0, 0, 0, 0},
    {1, 1, 0, 0, 0, 0, 0, 0, 0, 0},
    {1, 2, 1, 0, 0, 0, 0, 0, 0, 0},
    {1, 3, 3, 1, 0, 0, 0, 0, 0, 0},
    {1, 4, 6, 4, 1, 0, 0, 0, 0, 0},
    {1, 5, 10, 10, 5, 1, 0, 0, 0, 0},
    {1, 6, 15, 20, 15, 6, 1, 0, 0, 0},
    {1, 7, 21, 35, 35, 21, 7, 1, 0, 0},
    {1, 8, 28, 56, 70, 56, 28, 8, 1, 0},
    {1, 9, 36, 84, 126, 126, 84, 36, 9, 1}};
constexpr float FACT[10] = {1.f, 1.f, 2.f, 6.f, 24.f, 120.f,
                            720.f, 5040.f, 40320.f, 362880.f};
constexpr float IFC[10] = {1.f, 1.f, 0.5f, 1.f / 6.f, 1.f / 24.f,
                           1.f / 120.f, 1.f / 720.f, 1.f / 5040.f,
                           1.f / 40320.f, 1.f / 362880.f};

// Fused moment kernel (r0 known-good shape: 128 blocks x 256 threads,
// moment tables in VGPRs) + strictly-fewer-VALU micro-opts:
//   - P1 h-term factored as (d_i*i!) * (a^p/p!) * (b^q/q!)  (2 mults, was 3)
//   - P3 nested Horner over p,q (65 FMA, was ~110 ops)
// NOTE (R1 post-mortem): do NOT host M/N in SGPRs via readfirstlane (121
// values > ~102-SGPR cap) and do NOT widen to 512 threads (butterfly work
// scales with thread count). 256-thread VGPR version measured fastest.
__global__ __launch_bounds__(256, 1) void kf_moments(
    const float* __restrict__ visual, const float* __restrict__ text,
    const float* __restrict__ w_vis, const float* __restrict__ w_text,
    const float* __restrict__ bias, float* __restrict__ St) {
  const int b = blockIdx.x;
  const int tid = threadIdx.x;
  const int lane = tid & 63, wave = tid >> 6;
  __shared__ float Rw[4][66];
  __shared__ float fin[66];

  // ---------- P0: t-moments M_{p,q} = sum_t w^p x^q, p+q <= 10 ----------
  float mac[66];
#pragma unroll
  for (int r = 0; r < 66; ++r) mac[r] = 0.f;
#pragma unroll
  for (int j = 0; j < 4; ++j) {
    const int t = tid + 256 * j;
    const float w = w_vis[t];
    const float x = text[b * T_ + t];
    float wp[11], xq[11];
    wp[0] = 1.f;
    xq[0] = 1.f;
#pragma unroll
    for (int k = 1; k <= 10; ++k) {
      wp[k] = wp[k - 1] * w;
      xq[k] = xq[k - 1] * x;
    }
#pragma unroll
    for (int i = 0; i <= 10; ++i)
#pragma unroll
      for (int p = 0; p <= i; ++p)
        mac[i * (i + 1) / 2 + p] =
            fmaf(wp[p], xq[i - p], mac[i * (i + 1) / 2 + p]);
  }
#pragma unroll
  for (int m = 1; m <= 32; m <<= 1)
#pragma unroll
    for (int r = 0; r < 66; ++r) mac[r] += __shfl_xor(mac[r], m, 64);
  if (lane == 0) {
#pragma unroll
    for (int r = 0; r < 66; ++r) Rw[wave][r] = mac[r];
  }
  __syncthreads();
  if (tid < 66) fin[tid] = (Rw[0][tid] + Rw[1][tid]) + (Rw[2][tid] + Rw[3][tid]);
  __syncthreads();
  float M[66];
#pragma unroll
  for (int r = 0; r < 66; ++r) M[r] = fin[r];

  // ---------- P1 + P2: per-v eval and v-moments ----------
  float nac[55];
#pragma unroll
  for (int r = 0; r < 55; ++r) nac[r] = 0.f;
#pragma unroll
  for (int j = 0; j < 4; ++j) {
    const int v = tid + 256 * j;
    const float al = visual[b * V_ + v];
    const float be = w_text[v];
    const float ga = bias[v];
    float Ah[10], Bh[10];  // a^p/p!, b^q/q!
    Ah[0] = 1.f;
    Bh[0] = 1.f;
    float aw = 1.f, bw = 1.f;
#pragma unroll
    for (int k = 1; k <= 9; ++k) {
      aw *= al;
      Ah[k] = aw * IFC[k];
      bw *= be;
      Bh[k] = bw * IFC[k];
    }
    // dh_i = i! * d_i; Horner in ga with compile-time-folded constants
    float dh[10];
#pragma unroll
    for (int i = 0; i < 10; ++i) {
      float a = 0.f;
#pragma unroll
      for (int jj = 9; jj >= i; --jj)
        a = fmaf(a, ga, C9v[jj] * BN[jj][i] * FACT[i]);
      dh[i] = a;
    }
    float T1 = 0.f, T2 = 0.f;
    float h[55];
#pragma unroll
    for (int i = 0; i <= 9; ++i)
#pragma unroll
      for (int p = 0; p <= i; ++p) {
        const int ix = i * (i + 1) / 2 + p;
        const int ix2 = (i + 1) * (i + 2) / 2 + p;  // (p, q+1)
        h[ix] = dh[i] * Ah[p] * Bh[i - p];
        T1 = fmaf(h[ix], M[ix], T1);
        T2 = fmaf(h[ix], M[ix2], T2);
      }
    const float rd = 1.0f / T1;
    St[b * KK + T_ + v] = T2 * rd;  // text_score
    const float vod = al * rd;
#pragma unroll
    for (int r = 0; r < 55; ++r) nac[r] = fmaf(h[r], vod, nac[r]);
  }
#pragma unroll
  for (int m = 1; m <= 32; m <<= 1)
#pragma unroll
    for (int r = 0; r < 55; ++r) nac[r] += __shfl_xor(nac[r], m, 64);
  if (lane == 0) {
#pragma unroll
    for (int r = 0; r < 55; ++r) Rw[wave][r] = nac[r];
  }
  __syncthreads();
  if (tid < 55) fin[tid] = (Rw[0][tid] + Rw[1][tid]) + (Rw[2][tid] + Rw[3][tid]);
  __syncthreads();
  float N[55];
#pragma unroll
  for (int r = 0; r < 55; ++r) N[r] = fin[r];

  // ---------- P3: per-t eval, nested Horner ----------
#pragma unroll
  for (int j = 0; j < 4; ++j) {
    const int t = tid + 256 * j;
    const float w = w_vis[t];
    const float x = text[b * T_ + t];
    float wp[10], xq[10];
    wp[0] = 1.f;
    xq[0] = 1.f;
#pragma unroll
    for (int k = 1; k <= 9; ++k) {
      wp[k] = wp[k - 1] * w;
      xq[k] = xq[k - 1] * x;
    }
    float vs = 0.f;
#pragma unroll
    for (int p = 0; p <= 9; ++p) {
      float s = 0.f;
#pragma unroll
      for (int q = 0; q <= 9 - p; ++q)
        s = fmaf(xq[q], N[(p + q) * (p + q + 1) / 2 + p], s);
      vs = fmaf(wp[p], s, vs);
    }
    St[b * KK + t] = vs;  // visual_score
  }
}

// K3: split-K fp32 GEMM. part[z][b][c] = sum_{k in slab z} St[b][k]*Wcat[c][k].
// R3 change: K-slab = 32, grid (64 slabs, 8 c-tiles) = 512 blocks, LDS
// 33.8 KB -> 2 resident blocks/CU: one block's staging (vmcnt drain +
// barrier) overlaps the other's FMA stream. Micro-tile 8x8 = 1.0 B LDS/FMA.
// Bank check (stride 132): staging bank=(16*kq+row)%32 -> exact 2-way (free);
// compute reads: 4-lane/16-lane broadcast + 2-way (free).
#define KC3 32
__global__ __launch_bounds__(256, 2) void k3_gemm(
    const float* __restrict__ St, const float* __restrict__ W_fv,
    const float* __restrict__ W_ft, float* __restrict__ part) {
  __shared__ float Ss[KC3][132];  // [k][b], b = 0..127
  __shared__ float Ws[KC3][132];  // [k][c], c = 0..127
  const int zz = blockIdx.x;       // k-slab 0..63
  const int cb = blockIdx.y * 128; // c-tile
  const int ks = zz * KC3;
  const float* __restrict__ W = (ks < T_) ? (W_fv + ks) : (W_ft + (ks - T_));
  const int tid = threadIdx.x;
  const int kq = tid & 3, rr = tid >> 2;  // staging: k-quad 0..3, row 0..63

  // ---- stage St slab: 32k x 128b (transposed; k-contiguous loads) ----
#pragma unroll
  for (int jb = 0; jb < 2; ++jb) {
    const int brow = rr + 64 * jb;
#pragma unroll
    for (int jk = 0; jk < 2; ++jk) {
      const int k0 = 4 * kq + 16 * jk;
      float4 g = *(const float4*)&St[brow * KK + ks + k0];
      Ss[k0 + 0][brow] = g.x;
      Ss[k0 + 1][brow] = g.y;
      Ss[k0 + 2][brow] = g.z;
      Ss[k0 + 3][brow] = g.w;
    }
  }
  // ---- stage W slab: 32k x 128c ----
#pragma unroll
  for (int jc = 0; jc < 2; ++jc) {
    const int c = rr + 64 * jc;
#pragma unroll
    for (int jk = 0; jk < 2; ++jk) {
      const int k0 = 4 * kq + 16 * jk;
      float4 g = *(const float4*)&W[(cb + c) * 1024 + k0];
      Ws[k0 + 0][c] = g.x;
      Ws[k0 + 1][c] = g.y;
      Ws[k0 + 2][c] = g.z;
      Ws[k0 + 3][c] = g.w;
    }
  }
  __syncthreads();

  const int mc = tid & 15, mb = tid >> 4;
  float acc[8][8] = {};
#pragma unroll 4
  for (int k = 0; k < KC3; ++k) {
    const float4 s0 = *(const float4*)&Ss[k][4 * mb];
    const float4 s1 = *(const float4*)&Ss[k][4 * mb + 64];
    const float4 w0 = *(const float4*)&Ws[k][4 * mc];
    const float4 w1 = *(const float4*)&Ws[k][4 * mc + 64];
    const float sv[8] = {s0.x, s0.y, s0.z, s0.w, s1.x, s1.y, s1.z, s1.w};
    const float wv[8] = {w0.x, w0.y, w0.z, w0.w, w1.x, w1.y, w1.z, w1.w};
#pragma unroll
    for (int i = 0; i < 8; ++i)
#pragma unroll
      for (int u = 0; u < 8; ++u) acc[i][u] = fmaf(sv[i], wv[u], acc[i][u]);
  }

  float* __restrict__ P = part + (size_t)zz * (B_ * C_);
#pragma unroll
  for (int ih = 0; ih < 2; ++ih)
#pragma unroll
    for (int i = 0; i < 4; ++i) {
      const int row = 4 * mb + 64 * ih + i;
#pragma unroll
      for (int jh = 0; jh < 2; ++jh) {
        float4 o = make_float4(acc[ih * 4 + i][jh * 4 + 0],
                               acc[ih * 4 + i][jh * 4 + 1],
                               acc[ih * 4 + i][jh * 4 + 2],
                               acc[ih * 4 + i][jh * 4 + 3]);
        *(float4*)&P[row * C_ + cb + 4 * mc + 64 * jh] = o;
      }
    }
}

// K4: out[i] = relu(sum_{z<64} part[z][i] + b_fv[c] + b_ft[c]), float4-wide.
// part is 32 MB -> mostly L2-resident (4 MB/XCD x 8).
__global__ __launch_bounds__(256) void k4_reduce_biasrelu(
    const float* __restrict__ part, const float* __restrict__ b_fv,
    const float* __restrict__ b_ft, float* __restrict__ out) {
  const int i4 = (blockIdx.x * 256 + threadIdx.x) * 4;
  float4 s = *(const float4*)&part[i4];
#pragma unroll 8
  for (int z = 1; z < 64; ++z) {
    float4 p = *(const float4*)&part[(size_t)z * (B_ * C_) + i4];
    s.x += p.x;
    s.y += p.y;
    s.z += p.z;
    s.w += p.w;
  }
  const int c = i4 & (C_ - 1);
  float4 bf = *(const float4*)&b_fv[c];
  float4 bt = *(const float4*)&b_ft[c];
  float4 o;
  o.x = fmaxf(s.x + bf.x + bt.x, 0.f);
  o.y = fmaxf(s.y + bf.y + bt.y, 0.f);
  o.z = fmaxf(s.z + bf.z + bt.z, 0.f);
  o.w = fmaxf(s.w + bf.w + bt.w, 0.f);
  *(float4*)&out[i4] = o;
}

extern "C" void kernel_launch(void* const* d_in, const int* in_sizes, int n_in,
                              void* d_out, int out_size, void* d_ws, size_t ws_size,
                              hipStream_t stream) {
  const float* visual = (const float*)d_in[0];  // [B,V]
  const float* text   = (const float*)d_in[1];  // [B,T]
  const float* w_vis  = (const float*)d_in[2];  // [T]
  const float* w_text = (const float*)d_in[3];  // [V]
  const float* bias   = (const float*)d_in[4];  // [V]
  const float* W_fv   = (const float*)d_in[5];  // [C,T]
  const float* b_fv   = (const float*)d_in[6];  // [C]
  const float* W_ft   = (const float*)d_in[7];  // [C,V]
  const float* b_ft   = (const float*)d_in[8];  // [C]
  float* out = (float*)d_out;                   // [B,C]

  // ws layout (floats): St[B][2048] | part[64][B*C]   (~33 MB)
  float* St = (float*)d_ws;
  float* part = St + (size_t)B_ * KK;

  kf_moments<<<dim3(B_), dim3(256), 0, stream>>>(visual, text, w_vis, w_text,
                                                 bias, St);
  k3_gemm<<<dim3(64, 8), dim3(256), 0, stream>>>(St, W_fv, W_ft, part);
  k4_reduce_biasrelu<<<dim3(B_ * C_ / 1024), dim3(256), 0, stream>>>(
      part, b_fv, b_ft, out);
}